// Round 4
// baseline (535.938 us; speedup 1.0000x reference)
//
#include <hip/hip_runtime.h>
#include <hip/hip_bf16.h>
#include <stdint.h>

typedef __attribute__((ext_vector_type(8))) short short8;
typedef __attribute__((ext_vector_type(4))) float f32x4;

#define D 256
#define NYB 2  // N-tiles (256 cols) per block

static __device__ __forceinline__ float b2f(unsigned short u) {
  union { unsigned u; float f; } c; c.u = ((unsigned)u) << 16; return c.f;
}
static __device__ __forceinline__ unsigned short f2b(float f) {
  union { float f; unsigned u; } c; c.f = f;
  unsigned r = (c.u + 0x7FFFu + ((c.u >> 16) & 1u)) >> 16;
  return (unsigned short)r;
}

// ---------------- convert x (fp32 -> bf16, zero-pad rows to Mpad) ----------
__global__ void k_cvt_x(const float* __restrict__ x, unsigned short* __restrict__ xb,
                        long n_elems, long pad_elems) {
  long i4 = (long)blockIdx.x * 256 + threadIdx.x;
  if (i4 * 4 >= pad_elems) return;
  ushort4 o;
  if (i4 * 4 < n_elems) {
    float4 v = ((const float4*)x)[i4];
    o.x = f2b(v.x); o.y = f2b(v.y); o.z = f2b(v.z); o.w = f2b(v.w);
  } else {
    o.x = 0; o.y = 0; o.z = 0; o.w = 0;
  }
  ((ushort4*)xb)[i4] = o;
}

// ------------- convert + transpose weight: W[r][i][o] -> Wt[(r*256+o)][i] ---
__global__ void k_cvt_w(const float* __restrict__ w, unsigned short* __restrict__ wt,
                        int total) {
  int t = blockIdx.x * 256 + threadIdx.x;
  if (t >= total) return;
  int i = t & 255;         // k index
  int orow = t >> 8;       // r*256 + o
  int r = orow >> 8, o = orow & 255;
  wt[t] = f2b(w[((size_t)(r * 256 + i)) * 256 + o]);
}

// ---------------- GEMM: xt = xb @ Wt^T ------------------------------------
// Block: M=64 (full-K A panel, 32 KB LDS, staged once) x NYB N-tiles of 256.
// Grid (Mpad/64, 4) = 3128 blocks -> ~6 rounds of 512 slots (2 blocks/CU at
// 64 KB LDS): tail ~2% (was ~50% at 782 blocks / 768 slots).
// 4 waves, wave-tile 64x64 (acc 4x4): 16 ds_read_b128 per 32 MFMA (0.5).
// A and B reg-staged (no global_load_lds -> no vmcnt(0) barrier drains);
// B prefetched one K-step ahead in regs. LDS XOR-swizzle (16B chunk ^ row&7)
// on both write and read sides.
// xt stored column-permuted per 32-col block: stored = l15*2 + nb
// (true col = nb*16 + l15), packed 2xbf16 dword stores, 64B/16 lanes.
__global__ __launch_bounds__(256) void k_gemm(const unsigned short* __restrict__ A,
                                              const unsigned short* __restrict__ B,
                                              unsigned short* __restrict__ C,
                                              int ldc) {
  __shared__ __align__(16) char lA[64 * 512];   // [64 rows][32 x 16B]
  __shared__ __align__(16) char lB[256 * 128];  // [256 rows][8 x 16B]
  const int t = threadIdx.x;
  const int lane = t & 63;
  const int wave = t >> 6;
  const int l15 = lane & 15, lhi = lane >> 4;
  const size_t tm = (size_t)blockIdx.x * 64;
  const int y0 = blockIdx.y * NYB;

  // ---- stage A once: 8 x 16B per thread, linear global, swizzled ds_write
  uint4 ta[8];
#pragma unroll
  for (int it = 0; it < 8; ++it) {
    int s = it * 256 + t;
    int row = s >> 5, c = s & 31;
    ta[it] = *(const uint4*)(A + (tm + row) * 256 + c * 8);
  }
  // ---- prefetch B for q=0
  uint4 rb[8];
#pragma unroll
  for (int it = 0; it < 8; ++it) {
    int s = it * 256 + t;
    int row = s >> 3, c = s & 7;
    rb[it] = *(const uint4*)(B + ((size_t)(y0 * 256 + row)) * 256 + c * 8);
  }
#pragma unroll
  for (int it = 0; it < 8; ++it) {
    int s = it * 256 + t;
    int row = s >> 5, c = s & 31;
    *(uint4*)(lA + row * 512 + ((c ^ (row & 7)) * 16)) = ta[it];
  }

  f32x4 acc[4][4];
  for (int q = 0; q < NYB * 4; ++q) {
    const int kt = (q & 3) * 64;
    if (kt == 0) {
#pragma unroll
      for (int a = 0; a < 4; ++a)
#pragma unroll
        for (int b = 0; b < 4; ++b)
#pragma unroll
          for (int e = 0; e < 4; ++e) acc[a][b][e] = 0.f;
    }
    __syncthreads();  // previous iteration's lB readers done
#pragma unroll
    for (int it = 0; it < 8; ++it) {
      int s = it * 256 + t;
      int row = s >> 3, c = s & 7;
      *(uint4*)(lB + row * 128 + ((c ^ (row & 7)) * 16)) = rb[it];
    }
    if (q + 1 < NYB * 4) {
      int kt2 = ((q + 1) & 3) * 64;
      int y2 = y0 + ((q + 1) >> 2);
#pragma unroll
      for (int it = 0; it < 8; ++it) {
        int s = it * 256 + t;
        int row = s >> 3, c = s & 7;
        rb[it] = *(const uint4*)(B + ((size_t)(y2 * 256 + row)) * 256 + kt2 + c * 8);
      }
    }
    __syncthreads();  // lB visible

    const int ktc = kt >> 3;
    short8 af[4][2];
#pragma unroll
    for (int mi = 0; mi < 4; ++mi)
#pragma unroll
      for (int kk = 0; kk < 2; ++kk) {
        int R = mi * 16 + l15;
        int c = ktc + kk * 4 + lhi;
        af[mi][kk] = *(const short8*)(lA + R * 512 + ((c ^ (R & 7)) * 16));
      }
#pragma unroll
    for (int ni = 0; ni < 4; ++ni) {
      int R2 = wave * 64 + ni * 16 + l15;
      short8 b0 = *(const short8*)(lB + R2 * 128 + (((lhi) ^ (R2 & 7)) * 16));
      short8 b1 = *(const short8*)(lB + R2 * 128 + (((4 + lhi) ^ (R2 & 7)) * 16));
#pragma unroll
      for (int mi = 0; mi < 4; ++mi) {
        acc[mi][ni] = __builtin_amdgcn_mfma_f32_16x16x32_bf16(af[mi][0], b0, acc[mi][ni], 0, 0, 0);
        acc[mi][ni] = __builtin_amdgcn_mfma_f32_16x16x32_bf16(af[mi][1], b1, acc[mi][ni], 0, 0, 0);
      }
    }

    if ((q & 3) == 3) {  // end of K: store this y-tile
      const int tn = (y0 + (q >> 2)) * 256;
#pragma unroll
      for (int mi = 0; mi < 4; ++mi)
#pragma unroll
        for (int j = 0; j < 4; ++j) {
          size_t row = tm + mi * 16 + lhi * 4 + j;
#pragma unroll
          for (int bl = 0; bl < 2; ++bl) {
            unsigned pk = (unsigned)f2b(acc[mi][bl * 2][j]) |
                          ((unsigned)f2b(acc[mi][bl * 2 + 1][j]) << 16);
            *(unsigned*)(C + row * (size_t)ldc + tn + (wave * 2 + bl) * 32 + l15 * 2) = pk;
          }
        }
    }
  }
}

// ---------------- CSR build ------------------------------------------------
__global__ void k_zero(int* p, int n) {
  int i = blockIdx.x * 256 + threadIdx.x;
  if (i < n) p[i] = 0;
}
__global__ void k_deg(const int* __restrict__ ei, int* deg, int E) {
  int e = blockIdx.x * 256 + threadIdx.x;
  if (e < E) atomicAdd(&deg[ei[e]], 1);
}
__global__ void k_scan1(const int* __restrict__ deg, int* bsum, int n) {
  __shared__ int sm[256];
  int t = threadIdx.x, idx = blockIdx.x * 256 + t;
  sm[t] = idx < n ? deg[idx] : 0;
  __syncthreads();
  for (int off = 128; off; off >>= 1) {
    if (t < off) sm[t] += sm[t + off];
    __syncthreads();
  }
  if (t == 0) bsum[blockIdx.x] = sm[0];
}
__global__ void k_scan2(const int* __restrict__ bsum, int* boff, int* rowptr,
                        int nsc, int Nn) {
  __shared__ int sm[256];
  int t = threadIdx.x;
  int v = t < nsc ? bsum[t] : 0;
  sm[t] = v;
  __syncthreads();
  for (int off = 1; off < 256; off <<= 1) {
    int x = t >= off ? sm[t - off] : 0;
    __syncthreads();
    sm[t] += x;
    __syncthreads();
  }
  if (t < nsc) boff[t] = sm[t] - v;
  if (t == nsc - 1) rowptr[Nn] = sm[t];
}
__global__ void k_scan3(const int* __restrict__ deg, const int* __restrict__ boff,
                        int* rowptr, int* cursor, int n) {
  __shared__ int sm[256];
  int t = threadIdx.x, idx = blockIdx.x * 256 + t;
  int v = idx < n ? deg[idx] : 0;
  sm[t] = v;
  __syncthreads();
  for (int off = 1; off < 256; off <<= 1) {
    int x = t >= off ? sm[t - off] : 0;
    __syncthreads();
    sm[t] += x;
    __syncthreads();
  }
  if (idx < n) {
    int e = boff[blockIdx.x] + sm[t] - v;
    rowptr[idx] = e;
    cursor[idx] = e;
  }
}
__global__ void k_bin(const int* __restrict__ ei, const int* __restrict__ et,
                      int* cursor, unsigned* ect, int E) {
  int e = blockIdx.x * 256 + threadIdx.x;
  if (e >= E) return;
  int r = ei[e], c = ei[E + e], ty = et[e];
  int pos = atomicAdd(&cursor[r], 1);
  ect[pos] = (unsigned)c | ((unsigned)ty << 20);
}

// ---------------- gather: one wave per output row --------------------------
// xt rows are column-permuted (see k_gemm); accumulate in stored order, then
// un-permute through 1KB/wave LDS before bias+relu+coalesced float4 store.
__global__ __launch_bounds__(256) void k_gather(const unsigned* __restrict__ ect,
                                                const int* __restrict__ rowptr,
                                                const unsigned short* __restrict__ xt,
                                                const float* __restrict__ bias,
                                                float* __restrict__ out, int n, int ldxt) {
  __shared__ float sm[4][256];
  int lane = threadIdx.x & 63;
  int wid = threadIdx.x >> 6;
  int row = blockIdx.x * 4 + wid;
  if (row >= n) return;
  int s = rowptr[row], e = rowptr[row + 1];
  float a0 = 0.f, a1 = 0.f, a2 = 0.f, a3 = 0.f;
  unsigned myct = (s + lane < e) ? ect[s + lane] : 0u;
  int cnt = e - s;
  if (cnt > 64) cnt = 64;
  for (int i = 0; i < cnt; ++i) {
    unsigned ct = __shfl(myct, i);
    size_t base = (size_t)(ct & 0xFFFFFu) * ldxt + ((ct >> 20) << 8) + (lane << 2);
    ushort4 v = *(const ushort4*)(xt + base);
    a0 += b2f(v.x); a1 += b2f(v.y); a2 += b2f(v.z); a3 += b2f(v.w);
  }
  for (int i = s + 64; i < e; ++i) {
    unsigned ct = ect[i];
    size_t base = (size_t)(ct & 0xFFFFFu) * ldxt + ((ct >> 20) << 8) + (lane << 2);
    ushort4 v = *(const ushort4*)(xt + base);
    a0 += b2f(v.x); a1 += b2f(v.y); a2 += b2f(v.z); a3 += b2f(v.w);
  }
  // un-permute: stored p8 = lane*4+q  ->  true o = p8[7:5] | p8[0]<<4 | p8[4:1]
  int p0 = lane * 4;
  float av[4] = {a0, a1, a2, a3};
#pragma unroll
  for (int q = 0; q < 4; ++q) {
    int p8 = p0 + q;
    int o = (p8 & 224) | ((p8 & 1) << 4) | ((p8 & 31) >> 1);
    sm[wid][o] = av[q];
  }
  float4 v = *(const float4*)&sm[wid][lane * 4];
  float4 bb = ((const float4*)bias)[lane];
  float4 o;
  o.x = fmaxf(v.x + bb.x, 0.f);
  o.y = fmaxf(v.y + bb.y, 0.f);
  o.z = fmaxf(v.z + bb.z, 0.f);
  o.w = fmaxf(v.w + bb.w, 0.f);
  ((float4*)out)[(size_t)row * 64 + lane] = o;
}

extern "C" void kernel_launch(void* const* d_in, const int* in_sizes, int n_in,
                              void* d_out, int out_size, void* d_ws, size_t ws_size,
                              hipStream_t stream) {
  const float* x = (const float*)d_in[0];
  const int* ei = (const int*)d_in[1];
  const int* et = (const int*)d_in[2];
  const float* w = (const float*)d_in[3];
  const float* bias = (const float*)d_in[4];
  float* out = (float*)d_out;

  const int Nn = in_sizes[0] / D;        // 50000
  const int E = in_sizes[2];             // 800000
  const int R = in_sizes[3] / (D * D);   // 8
  const int Mpad = ((Nn + 63) / 64) * 64;   // 50048
  const int NC = R * D;                  // 2048

  char* p = (char*)d_ws;
  auto alloc = [&](size_t bytes) -> char* {
    char* q = p;
    p += (bytes + 255) & ~(size_t)255;
    return q;
  };
  unsigned short* xt = (unsigned short*)alloc((size_t)Mpad * NC * 2);
  unsigned short* xb = (unsigned short*)alloc((size_t)Mpad * D * 2);
  unsigned short* wt = (unsigned short*)alloc((size_t)NC * D * 2);
  int* rowptr = (int*)alloc((size_t)(Nn + 1) * 4);
  int* cursor = (int*)alloc((size_t)Nn * 4);
  int* deg = (int*)alloc((size_t)Nn * 4);
  int* bsum = (int*)alloc(1024);
  int* boff = (int*)alloc(1024);
  unsigned* ect = (unsigned*)alloc((size_t)E * 4);

  const int nsc = (Nn + 255) / 256;

  // CSR build
  hipLaunchKernelGGL(k_zero, dim3(nsc), dim3(256), 0, stream, deg, Nn);
  hipLaunchKernelGGL(k_deg, dim3((E + 255) / 256), dim3(256), 0, stream, ei, deg, E);
  hipLaunchKernelGGL(k_scan1, dim3(nsc), dim3(256), 0, stream, deg, bsum, Nn);
  hipLaunchKernelGGL(k_scan2, dim3(1), dim3(256), 0, stream, bsum, boff, rowptr, nsc, Nn);
  hipLaunchKernelGGL(k_scan3, dim3(nsc), dim3(256), 0, stream, deg, boff, rowptr, cursor, Nn);
  hipLaunchKernelGGL(k_bin, dim3((E + 255) / 256), dim3(256), 0, stream, ei, et, cursor, ect, E);

  // dense transform
  hipLaunchKernelGGL(k_cvt_x, dim3(Mpad / 4), dim3(256), 0, stream, x, xb,
                     (long)Nn * D, (long)Mpad * D);
  hipLaunchKernelGGL(k_cvt_w, dim3((NC * D + 255) / 256), dim3(256), 0, stream, w, wt, NC * D);
  hipLaunchKernelGGL(k_gemm, dim3(Mpad / 64, NC / (256 * NYB)), dim3(256), 0, stream,
                     xb, wt, xt, NC);

  // gather + bias + relu
  hipLaunchKernelGGL(k_gather, dim3((Nn + 3) / 4), dim3(256), 0, stream, ect, rowptr,
                     xt, bias, out, Nn, NC);
}

// Round 5
// 363.582 us; speedup vs baseline: 1.4740x; 1.4740x over previous
//
#include <hip/hip_runtime.h>
#include <hip/hip_bf16.h>
#include <stdint.h>

typedef __attribute__((ext_vector_type(8))) short short8;
typedef __attribute__((ext_vector_type(4))) float f32x4;

#define D 256
#define NTY 4  // y-tiles (128 cols) per block

static __device__ __forceinline__ float b2f(unsigned short u) {
  union { unsigned u; float f; } c; c.u = ((unsigned)u) << 16; return c.f;
}
static __device__ __forceinline__ unsigned short f2b(float f) {
  union { float f; unsigned u; } c; c.f = f;
  unsigned r = (c.u + 0x7FFFu + ((c.u >> 16) & 1u)) >> 16;
  return (unsigned short)r;
}

// async global->LDS, 16B per lane, wave-uniform LDS base + lane*16
static __device__ __forceinline__ void gload16(const void* g, void* l) {
  __builtin_amdgcn_global_load_lds(
      (const __attribute__((address_space(1))) unsigned int*)g,
      (__attribute__((address_space(3))) unsigned int*)l, 16, 0, 0);
}

// ---------------- convert x (fp32 -> bf16, zero-pad rows to Mpad) ----------
__global__ void k_cvt_x(const float* __restrict__ x, unsigned short* __restrict__ xb,
                        long n_elems, long pad_elems) {
  long i4 = (long)blockIdx.x * 256 + threadIdx.x;
  if (i4 * 4 >= pad_elems) return;
  ushort4 o;
  if (i4 * 4 < n_elems) {
    float4 v = ((const float4*)x)[i4];
    o.x = f2b(v.x); o.y = f2b(v.y); o.z = f2b(v.z); o.w = f2b(v.w);
  } else {
    o.x = 0; o.y = 0; o.z = 0; o.w = 0;
  }
  ((ushort4*)xb)[i4] = o;
}

// ------------- convert + transpose weight: W[r][i][o] -> Wt[(r*256+o)][i] ---
__global__ void k_cvt_w(const float* __restrict__ w, unsigned short* __restrict__ wt,
                        int total) {
  int t = blockIdx.x * 256 + threadIdx.x;
  if (t >= total) return;
  int i = t & 255;         // k index
  int orow = t >> 8;       // r*256 + o
  int r = orow >> 8, o = orow & 255;
  wt[t] = f2b(w[((size_t)(r * 256 + i)) * 256 + o]);
}

// ---------------- GEMM: xt = xb @ Wt^T, A-resident, N-loop inside block ----
// ROUND-3 PROVEN INNER LOOP (gload16 staging, VGPR=76, no spill — round 4's
// reg-staged variant spilled and tripled WRITE_SIZE; do not reg-stage both).
// tile M=64 (A panel [64][256] bf16 = 32KB LDS, fetched once per block),
// NTY=4 y-tiles of 128 cols per block; grid (Mpad/64, 4) = 3128 blocks over
// 768 slots (48KB LDS -> 3 blocks/CU) = 4.07 rounds -> tail ~2% (round 3's
// 782/768 grid wasted ~half the dispatch in a 14-block second round).
// B staged [128][64] bf16 = 16KB per K-step via global_load_lds (linear LDS
// dest + inverse-swizzled per-lane global src; chunk ^ row&7 both sides).
// xt stored COLUMN-PERMUTED within each 32-col block: stored = l15*2 + ni
// (true col = ni*16 + l15) so the epilogue writes packed dwords, 64B/16 lanes.
__global__ __launch_bounds__(256) void k_gemm(const unsigned short* __restrict__ A,
                                              const unsigned short* __restrict__ B,
                                              unsigned short* __restrict__ C,
                                              int ldc) {
  __shared__ __align__(16) char lA[64 * 512];    // [64 rows][32 chunks of 16B]
  __shared__ __align__(16) char lB[128 * 128];   // [128 rows][8 chunks of 16B]
  const int t = threadIdx.x;
  const int lane = t & 63;
  const int wave = t >> 6;
  const int l15 = lane & 15, lhi = lane >> 4;
  const size_t tm = (size_t)blockIdx.x * 64;
  const int y0 = blockIdx.y * NTY;

  // ---- stage A once: 2048 chunks, 8 per thread ----
#pragma unroll
  for (int it = 0; it < 8; ++it) {
    int s = it * 256 + t;
    int row = s >> 5, c = s & 31;
    gload16(A + (tm + row) * 256 + ((c ^ (row & 7)) * 8),
            lA + (it * 256 + wave * 64) * 16);
  }

  for (int y = y0; y < y0 + NTY; ++y) {
    const int tn = y * 128;
    f32x4 acc[4][2];
#pragma unroll
    for (int a = 0; a < 4; ++a)
#pragma unroll
      for (int b = 0; b < 2; ++b)
#pragma unroll
        for (int e = 0; e < 4; ++e) acc[a][b][e] = 0.f;

    for (int kt = 0; kt < 256; kt += 64) {
      __syncthreads();  // previous readers done (and A/B stores drained)
#pragma unroll
      for (int it = 0; it < 4; ++it) {
        int s = it * 256 + t;
        int row = s >> 3, c = s & 7;
        gload16(B + (tn + row) * 256 + kt + ((c ^ (row & 7)) * 8),
                lB + (it * 256 + wave * 64) * 16);
      }
      __syncthreads();  // barrier drain waits vmcnt(0): B (and A) ready

      short8 af[4][2], bfv[2][2];
      const int ktc = kt >> 3;
#pragma unroll
      for (int mi = 0; mi < 4; ++mi) {
#pragma unroll
        for (int kk = 0; kk < 2; ++kk) {
          int R = mi * 16 + l15;
          int c = ktc + kk * 4 + lhi;
          af[mi][kk] = *(const short8*)(lA + R * 512 + ((c ^ (R & 7)) * 16));
        }
      }
#pragma unroll
      for (int ni = 0; ni < 2; ++ni) {
#pragma unroll
        for (int kk = 0; kk < 2; ++kk) {
          int R2 = wave * 32 + ni * 16 + l15;
          int c2 = kk * 4 + lhi;
          bfv[ni][kk] = *(const short8*)(lB + R2 * 128 + ((c2 ^ (R2 & 7)) * 16));
        }
      }
#pragma unroll
      for (int mi = 0; mi < 4; ++mi) {
#pragma unroll
        for (int ni = 0; ni < 2; ++ni) {
          acc[mi][ni] = __builtin_amdgcn_mfma_f32_16x16x32_bf16(af[mi][0], bfv[ni][0], acc[mi][ni], 0, 0, 0);
          acc[mi][ni] = __builtin_amdgcn_mfma_f32_16x16x32_bf16(af[mi][1], bfv[ni][1], acc[mi][ni], 0, 0, 0);
        }
      }
    }
    // epilogue: per (mi,j) pack 2 bf16 -> dword; 16 lanes = 64B contiguous
#pragma unroll
    for (int mi = 0; mi < 4; ++mi) {
#pragma unroll
      for (int j = 0; j < 4; ++j) {
        size_t row = tm + mi * 16 + lhi * 4 + j;
        unsigned pk = (unsigned)f2b(acc[mi][0][j]) | ((unsigned)f2b(acc[mi][1][j]) << 16);
        *(unsigned*)(C + row * (size_t)ldc + tn + wave * 32 + l15 * 2) = pk;
      }
    }
  }
}

// ---------------- CSR build ------------------------------------------------
__global__ void k_zero(int* p, int n) {
  int i = blockIdx.x * 256 + threadIdx.x;
  if (i < n) p[i] = 0;
}
__global__ void k_deg(const int* __restrict__ ei, int* deg, int E) {
  int e = blockIdx.x * 256 + threadIdx.x;
  if (e < E) atomicAdd(&deg[ei[e]], 1);
}
__global__ void k_scan1(const int* __restrict__ deg, int* bsum, int n) {
  __shared__ int sm[256];
  int t = threadIdx.x, idx = blockIdx.x * 256 + t;
  sm[t] = idx < n ? deg[idx] : 0;
  __syncthreads();
  for (int off = 128; off; off >>= 1) {
    if (t < off) sm[t] += sm[t + off];
    __syncthreads();
  }
  if (t == 0) bsum[blockIdx.x] = sm[0];
}
__global__ void k_scan2(const int* __restrict__ bsum, int* boff, int* rowptr,
                        int nsc, int Nn) {
  __shared__ int sm[256];
  int t = threadIdx.x;
  int v = t < nsc ? bsum[t] : 0;
  sm[t] = v;
  __syncthreads();
  for (int off = 1; off < 256; off <<= 1) {
    int x = t >= off ? sm[t - off] : 0;
    __syncthreads();
    sm[t] += x;
    __syncthreads();
  }
  if (t < nsc) boff[t] = sm[t] - v;
  if (t == nsc - 1) rowptr[Nn] = sm[t];
}
__global__ void k_scan3(const int* __restrict__ deg, const int* __restrict__ boff,
                        int* rowptr, int* cursor, int n) {
  __shared__ int sm[256];
  int t = threadIdx.x, idx = blockIdx.x * 256 + t;
  int v = idx < n ? deg[idx] : 0;
  sm[t] = v;
  __syncthreads();
  for (int off = 1; off < 256; off <<= 1) {
    int x = t >= off ? sm[t - off] : 0;
    __syncthreads();
    sm[t] += x;
    __syncthreads();
  }
  if (idx < n) {
    int e = boff[blockIdx.x] + sm[t] - v;
    rowptr[idx] = e;
    cursor[idx] = e;
  }
}
__global__ void k_bin(const int* __restrict__ ei, const int* __restrict__ et,
                      int* cursor, unsigned* ect, int E) {
  int e = blockIdx.x * 256 + threadIdx.x;
  if (e >= E) return;
  int r = ei[e], c = ei[E + e], ty = et[e];
  int pos = atomicAdd(&cursor[r], 1);
  ect[pos] = (unsigned)c | ((unsigned)ty << 20);
}

// ---------------- gather: one wave per output row --------------------------
// xt rows are column-permuted (see k_gemm); accumulate in stored order, then
// un-permute through 1KB/wave LDS before bias+relu+coalesced float4 store.
__global__ __launch_bounds__(256) void k_gather(const unsigned* __restrict__ ect,
                                                const int* __restrict__ rowptr,
                                                const unsigned short* __restrict__ xt,
                                                const float* __restrict__ bias,
                                                float* __restrict__ out, int n, int ldxt) {
  __shared__ float sm[4][256];
  int lane = threadIdx.x & 63;
  int wid = threadIdx.x >> 6;
  int row = blockIdx.x * 4 + wid;
  if (row >= n) return;
  int s = rowptr[row], e = rowptr[row + 1];
  float a0 = 0.f, a1 = 0.f, a2 = 0.f, a3 = 0.f;
  unsigned myct = (s + lane < e) ? ect[s + lane] : 0u;
  int cnt = e - s;
  if (cnt > 64) cnt = 64;
  for (int i = 0; i < cnt; ++i) {
    unsigned ct = __shfl(myct, i);
    size_t base = (size_t)(ct & 0xFFFFFu) * ldxt + ((ct >> 20) << 8) + (lane << 2);
    ushort4 v = *(const ushort4*)(xt + base);
    a0 += b2f(v.x); a1 += b2f(v.y); a2 += b2f(v.z); a3 += b2f(v.w);
  }
  for (int i = s + 64; i < e; ++i) {
    unsigned ct = ect[i];
    size_t base = (size_t)(ct & 0xFFFFFu) * ldxt + ((ct >> 20) << 8) + (lane << 2);
    ushort4 v = *(const ushort4*)(xt + base);
    a0 += b2f(v.x); a1 += b2f(v.y); a2 += b2f(v.z); a3 += b2f(v.w);
  }
  // un-permute: stored p8 = lane*4+q  ->  true o = p8[7:5] | p8[0]<<4 | p8[4:1]
  int p0 = lane * 4;
  float av[4] = {a0, a1, a2, a3};
#pragma unroll
  for (int q = 0; q < 4; ++q) {
    int p8 = p0 + q;
    int o = (p8 & 224) | ((p8 & 1) << 4) | ((p8 & 31) >> 1);
    sm[wid][o] = av[q];
  }
  float4 v = *(const float4*)&sm[wid][lane * 4];
  float4 bb = ((const float4*)bias)[lane];
  float4 o;
  o.x = fmaxf(v.x + bb.x, 0.f);
  o.y = fmaxf(v.y + bb.y, 0.f);
  o.z = fmaxf(v.z + bb.z, 0.f);
  o.w = fmaxf(v.w + bb.w, 0.f);
  ((float4*)out)[(size_t)row * 64 + lane] = o;
}

extern "C" void kernel_launch(void* const* d_in, const int* in_sizes, int n_in,
                              void* d_out, int out_size, void* d_ws, size_t ws_size,
                              hipStream_t stream) {
  const float* x = (const float*)d_in[0];
  const int* ei = (const int*)d_in[1];
  const int* et = (const int*)d_in[2];
  const float* w = (const float*)d_in[3];
  const float* bias = (const float*)d_in[4];
  float* out = (float*)d_out;

  const int Nn = in_sizes[0] / D;        // 50000
  const int E = in_sizes[2];             // 800000
  const int R = in_sizes[3] / (D * D);   // 8
  const int Mpad = ((Nn + 63) / 64) * 64;   // 50048
  const int NC = R * D;                  // 2048

  char* p = (char*)d_ws;
  auto alloc = [&](size_t bytes) -> char* {
    char* q = p;
    p += (bytes + 255) & ~(size_t)255;
    return q;
  };
  unsigned short* xt = (unsigned short*)alloc((size_t)Mpad * NC * 2);
  unsigned short* xb = (unsigned short*)alloc((size_t)Mpad * D * 2);
  unsigned short* wt = (unsigned short*)alloc((size_t)NC * D * 2);
  int* rowptr = (int*)alloc((size_t)(Nn + 1) * 4);
  int* cursor = (int*)alloc((size_t)Nn * 4);
  int* deg = (int*)alloc((size_t)Nn * 4);
  int* bsum = (int*)alloc(1024);
  int* boff = (int*)alloc(1024);
  unsigned* ect = (unsigned*)alloc((size_t)E * 4);

  const int nsc = (Nn + 255) / 256;

  // CSR build
  hipLaunchKernelGGL(k_zero, dim3(nsc), dim3(256), 0, stream, deg, Nn);
  hipLaunchKernelGGL(k_deg, dim3((E + 255) / 256), dim3(256), 0, stream, ei, deg, E);
  hipLaunchKernelGGL(k_scan1, dim3(nsc), dim3(256), 0, stream, deg, bsum, Nn);
  hipLaunchKernelGGL(k_scan2, dim3(1), dim3(256), 0, stream, bsum, boff, rowptr, nsc, Nn);
  hipLaunchKernelGGL(k_scan3, dim3(nsc), dim3(256), 0, stream, deg, boff, rowptr, cursor, Nn);
  hipLaunchKernelGGL(k_bin, dim3((E + 255) / 256), dim3(256), 0, stream, ei, et, cursor, ect, E);

  // dense transform
  hipLaunchKernelGGL(k_cvt_x, dim3(Mpad / 4), dim3(256), 0, stream, x, xb,
                     (long)Nn * D, (long)Mpad * D);
  hipLaunchKernelGGL(k_cvt_w, dim3((NC * D + 255) / 256), dim3(256), 0, stream, w, wt, NC * D);
  hipLaunchKernelGGL(k_gemm, dim3(Mpad / 64, NC / (128 * NTY)), dim3(256), 0, stream,
                     xb, wt, xt, NC);

  // gather + bias + relu
  hipLaunchKernelGGL(k_gather, dim3((Nn + 3) / 4), dim3(256), 0, stream, ect, rowptr,
                     xt, bias, out, Nn, NC);
}

// Round 6
// 356.184 us; speedup vs baseline: 1.5047x; 1.0208x over previous
//
#include <hip/hip_runtime.h>
#include <hip/hip_bf16.h>
#include <stdint.h>

typedef __attribute__((ext_vector_type(8))) short short8;
typedef __attribute__((ext_vector_type(4))) float f32x4;

#define D 256
#define NTY 4  // y-tiles (128 cols) per block in k_gemm

static __device__ __forceinline__ float b2f(unsigned short u) {
  union { unsigned u; float f; } c; c.u = ((unsigned)u) << 16; return c.f;
}
static __device__ __forceinline__ unsigned short f2b(float f) {
  union { float f; unsigned u; } c; c.f = f;
  unsigned r = (c.u + 0x7FFFu + ((c.u >> 16) & 1u)) >> 16;
  return (unsigned short)r;
}

// async global->LDS, 16B per lane, wave-uniform LDS base + lane*16
static __device__ __forceinline__ void gload16(const void* g, void* l) {
  __builtin_amdgcn_global_load_lds(
      (const __attribute__((address_space(1))) unsigned int*)g,
      (__attribute__((address_space(3))) unsigned int*)l, 16, 0, 0);
}

// ---- fused convert: x (fp32->bf16, pad) + W transpose (W[r][i][o]->Wt[ro][i])
__global__ void k_cvt_xw(const float* __restrict__ x, unsigned short* __restrict__ xb,
                         long n_elems, long pad_elems, int xblocks,
                         const float* __restrict__ w, unsigned short* __restrict__ wt) {
  if (blockIdx.x < (unsigned)xblocks) {
    long i4 = (long)blockIdx.x * 256 + threadIdx.x;
    if (i4 * 4 >= pad_elems) return;
    ushort4 o;
    if (i4 * 4 < n_elems) {
      float4 v = ((const float4*)x)[i4];
      o.x = f2b(v.x); o.y = f2b(v.y); o.z = f2b(v.z); o.w = f2b(v.w);
    } else {
      o.x = 0; o.y = 0; o.z = 0; o.w = 0;
    }
    ((ushort4*)xb)[i4] = o;
  } else {
    int t = (blockIdx.x - xblocks) * 256 + threadIdx.x;
    int i = t & 255;         // k index
    int orow = t >> 8;       // r*256 + o
    int r = orow >> 8, o = orow & 255;
    wt[t] = f2b(w[((size_t)(r * 256 + i)) * 256 + o]);
  }
}

// ---------------- GEMM: xt = xb @ Wt^T, A-resident, N-loop inside block ----
// PROVEN round-5 kernel (90 µs, VGPR=80, no spill) — unchanged.
__global__ __launch_bounds__(256) void k_gemm(const unsigned short* __restrict__ A,
                                              const unsigned short* __restrict__ B,
                                              unsigned short* __restrict__ C,
                                              int ldc) {
  __shared__ __align__(16) char lA[64 * 512];    // [64 rows][32 chunks of 16B]
  __shared__ __align__(16) char lB[128 * 128];   // [128 rows][8 chunks of 16B]
  const int t = threadIdx.x;
  const int lane = t & 63;
  const int wave = t >> 6;
  const int l15 = lane & 15, lhi = lane >> 4;
  const size_t tm = (size_t)blockIdx.x * 64;
  const int y0 = blockIdx.y * NTY;

#pragma unroll
  for (int it = 0; it < 8; ++it) {
    int s = it * 256 + t;
    int row = s >> 5, c = s & 31;
    gload16(A + (tm + row) * 256 + ((c ^ (row & 7)) * 8),
            lA + (it * 256 + wave * 64) * 16);
  }

  for (int y = y0; y < y0 + NTY; ++y) {
    const int tn = y * 128;
    f32x4 acc[4][2];
#pragma unroll
    for (int a = 0; a < 4; ++a)
#pragma unroll
      for (int b = 0; b < 2; ++b)
#pragma unroll
        for (int e = 0; e < 4; ++e) acc[a][b][e] = 0.f;

    for (int kt = 0; kt < 256; kt += 64) {
      __syncthreads();
#pragma unroll
      for (int it = 0; it < 4; ++it) {
        int s = it * 256 + t;
        int row = s >> 3, c = s & 7;
        gload16(B + (tn + row) * 256 + kt + ((c ^ (row & 7)) * 8),
                lB + (it * 256 + wave * 64) * 16);
      }
      __syncthreads();

      short8 af[4][2], bfv[2][2];
      const int ktc = kt >> 3;
#pragma unroll
      for (int mi = 0; mi < 4; ++mi) {
#pragma unroll
        for (int kk = 0; kk < 2; ++kk) {
          int R = mi * 16 + l15;
          int c = ktc + kk * 4 + lhi;
          af[mi][kk] = *(const short8*)(lA + R * 512 + ((c ^ (R & 7)) * 16));
        }
      }
#pragma unroll
      for (int ni = 0; ni < 2; ++ni) {
#pragma unroll
        for (int kk = 0; kk < 2; ++kk) {
          int R2 = wave * 32 + ni * 16 + l15;
          int c2 = kk * 4 + lhi;
          bfv[ni][kk] = *(const short8*)(lB + R2 * 128 + ((c2 ^ (R2 & 7)) * 16));
        }
      }
#pragma unroll
      for (int mi = 0; mi < 4; ++mi) {
#pragma unroll
        for (int ni = 0; ni < 2; ++ni) {
          acc[mi][ni] = __builtin_amdgcn_mfma_f32_16x16x32_bf16(af[mi][0], bfv[ni][0], acc[mi][ni], 0, 0, 0);
          acc[mi][ni] = __builtin_amdgcn_mfma_f32_16x16x32_bf16(af[mi][1], bfv[ni][1], acc[mi][ni], 0, 0, 0);
        }
      }
    }
#pragma unroll
    for (int mi = 0; mi < 4; ++mi) {
#pragma unroll
      for (int j = 0; j < 4; ++j) {
        size_t row = tm + mi * 16 + lhi * 4 + j;
        unsigned pk = (unsigned)f2b(acc[mi][0][j]) | ((unsigned)f2b(acc[mi][1][j]) << 16);
        *(unsigned*)(C + row * (size_t)ldc + tn + wave * 32 + l15 * 2) = pk;
      }
    }
  }
}

// ---------------- CSR build ------------------------------------------------
__global__ void k_deg(const int* __restrict__ ei, int* deg, int E) {
  int e = blockIdx.x * 256 + threadIdx.x;
  if (e < E) atomicAdd(&deg[ei[e]], 1);
}
__global__ void k_scan1(const int* __restrict__ deg, int* bsum, int n) {
  __shared__ int sm[256];
  int t = threadIdx.x, idx = blockIdx.x * 256 + t;
  sm[t] = idx < n ? deg[idx] : 0;
  __syncthreads();
  for (int off = 128; off; off >>= 1) {
    if (t < off) sm[t] += sm[t + off];
    __syncthreads();
  }
  if (t == 0) bsum[blockIdx.x] = sm[0];
}
// fused scan2+scan3: every block redundantly scans the block-sums (nsc<=256),
// then does its local exclusive scan of deg -> rowptr/cursor.
__global__ void k_scan23(const int* __restrict__ deg, const int* __restrict__ bsum,
                         int* rowptr, int* cursor, int nsc, int n) {
  __shared__ int sb[256];
  __shared__ int sm[256];
  int t = threadIdx.x, idx = blockIdx.x * 256 + t;
  int bv = t < nsc ? bsum[t] : 0;
  sb[t] = bv;
  __syncthreads();
  for (int off = 1; off < 256; off <<= 1) {
    int x = t >= off ? sb[t - off] : 0;
    __syncthreads();
    sb[t] += x;
    __syncthreads();
  }
  int v = idx < n ? deg[idx] : 0;
  sm[t] = v;
  __syncthreads();
  for (int off = 1; off < 256; off <<= 1) {
    int x = t >= off ? sm[t - off] : 0;
    __syncthreads();
    sm[t] += x;
    __syncthreads();
  }
  int boff = sb[blockIdx.x] - bsum[blockIdx.x];  // exclusive block offset
  if (idx < n) {
    int e = boff + sm[t] - v;
    rowptr[idx] = e;
    cursor[idx] = e;
  }
  if (blockIdx.x == 0 && t == 0) rowptr[n] = sb[nsc - 1];
}
__global__ void k_bin(const int* __restrict__ ei, const int* __restrict__ et,
                      int* cursor, unsigned* ect, int E) {
  int e = blockIdx.x * 256 + threadIdx.x;
  if (e >= E) return;
  int r = ei[e], c = ei[E + e], ty = et[e];
  int pos = atomicAdd(&cursor[r], 1);
  ect[pos] = (unsigned)c | ((unsigned)ty << 20);
}

// ---------------- gather v2: one wave per output row, 2 edges/iteration ----
// lane-halves: lanes 0-31 take even edge, 32-63 odd edge; each lane reads
// 16B (8 bf16) of the 512B row -> half the loop trips vs v1's 8B/lane.
// Halves combined with one shfl_xor(32) per accumulator. xt rows are
// column-permuted (see k_gemm); un-permute via 1KB/wave LDS at the end.
__global__ __launch_bounds__(256) void k_gather(const unsigned* __restrict__ ect,
                                                const int* __restrict__ rowptr,
                                                const unsigned short* __restrict__ xt,
                                                const float* __restrict__ bias,
                                                float* __restrict__ out, int n, int ldxt) {
  __shared__ float sm[4][256];
  const int lane = threadIdx.x & 63;
  const int wid = threadIdx.x >> 6;
  const int h = lane >> 5;
  const int sl = lane & 31;
  const int row = blockIdx.x * 4 + wid;
  if (row >= n) return;
  const int s = rowptr[row], e = rowptr[row + 1];
  const int cnt = e - s;
  float a[8] = {0.f, 0.f, 0.f, 0.f, 0.f, 0.f, 0.f, 0.f};
  unsigned myct = (s + lane < e) ? ect[s + lane] : 0u;
  int c1 = cnt > 64 ? 64 : cnt;
  for (int i = 0; i < c1; i += 2) {
    int j = i + h;
    unsigned ct = __shfl(myct, j);
    if (j < c1) {
      size_t base = (size_t)(ct & 0xFFFFFu) * ldxt + ((ct >> 20) << 8) + (sl << 3);
      short8 v = *(const short8*)(xt + base);
#pragma unroll
      for (int k = 0; k < 8; ++k) a[k] += b2f((unsigned short)v[k]);
    }
  }
  for (int i = s + 64; i < e; i += 2) {
    int j = i + h;
    if (j < e) {
      unsigned ct = ect[j];
      size_t base = (size_t)(ct & 0xFFFFFu) * ldxt + ((ct >> 20) << 8) + (sl << 3);
      short8 v = *(const short8*)(xt + base);
#pragma unroll
      for (int k = 0; k < 8; ++k) a[k] += b2f((unsigned short)v[k]);
    }
  }
#pragma unroll
  for (int k = 0; k < 8; ++k) a[k] += __shfl_xor(a[k], 32);
  // un-permute (half 0 holds full sums): stored p8 -> true col o
  if (h == 0) {
#pragma unroll
    for (int k = 0; k < 8; ++k) {
      int p8 = sl * 8 + k;
      int o = (p8 & 224) | ((p8 & 1) << 4) | ((p8 & 31) >> 1);
      sm[wid][o] = a[k];
    }
  }
  // same-wave LDS RAW: compiler inserts lgkmcnt wait; no __syncthreads needed
  float4 v = *(const float4*)&sm[wid][lane * 4];
  float4 bb = ((const float4*)bias)[lane];
  float4 o;
  o.x = fmaxf(v.x + bb.x, 0.f);
  o.y = fmaxf(v.y + bb.y, 0.f);
  o.z = fmaxf(v.z + bb.z, 0.f);
  o.w = fmaxf(v.w + bb.w, 0.f);
  ((float4*)out)[(size_t)row * 64 + lane] = o;
}

extern "C" void kernel_launch(void* const* d_in, const int* in_sizes, int n_in,
                              void* d_out, int out_size, void* d_ws, size_t ws_size,
                              hipStream_t stream) {
  const float* x = (const float*)d_in[0];
  const int* ei = (const int*)d_in[1];
  const int* et = (const int*)d_in[2];
  const float* w = (const float*)d_in[3];
  const float* bias = (const float*)d_in[4];
  float* out = (float*)d_out;

  const int Nn = in_sizes[0] / D;        // 50000
  const int E = in_sizes[2];             // 800000
  const int R = in_sizes[3] / (D * D);   // 8
  const int Mpad = ((Nn + 63) / 64) * 64;   // 50048
  const int NC = R * D;                  // 2048

  char* p = (char*)d_ws;
  auto alloc = [&](size_t bytes) -> char* {
    char* q = p;
    p += (bytes + 255) & ~(size_t)255;
    return q;
  };
  unsigned short* xt = (unsigned short*)alloc((size_t)Mpad * NC * 2);
  unsigned short* xb = (unsigned short*)alloc((size_t)Mpad * D * 2);
  unsigned short* wt = (unsigned short*)alloc((size_t)NC * D * 2);
  int* rowptr = (int*)alloc((size_t)(Nn + 1) * 4);
  int* cursor = (int*)alloc((size_t)Nn * 4);
  int* deg = (int*)alloc((size_t)Nn * 4);
  int* bsum = (int*)alloc(1024);
  unsigned* ect = (unsigned*)alloc((size_t)E * 4);

  const int nsc = (Nn + 255) / 256;
  const int xblocks = Mpad / 4;

  // CSR build
  hipMemsetAsync(deg, 0, (size_t)Nn * 4, stream);
  hipLaunchKernelGGL(k_deg, dim3((E + 255) / 256), dim3(256), 0, stream, ei, deg, E);
  hipLaunchKernelGGL(k_scan1, dim3(nsc), dim3(256), 0, stream, deg, bsum, Nn);
  hipLaunchKernelGGL(k_scan23, dim3(nsc), dim3(256), 0, stream, deg, bsum,
                     rowptr, cursor, nsc, Nn);
  hipLaunchKernelGGL(k_bin, dim3((E + 255) / 256), dim3(256), 0, stream, ei, et, cursor, ect, E);

  // dense transform
  hipLaunchKernelGGL(k_cvt_xw, dim3(xblocks + (NC * D) / 256), dim3(256), 0, stream,
                     x, xb, (long)Nn * D, (long)Mpad * D, xblocks, w, wt);
  hipLaunchKernelGGL(k_gemm, dim3(Mpad / 64, NC / (128 * NTY)), dim3(256), 0, stream,
                     xb, wt, xt, NC);

  // gather + bias + relu
  hipLaunchKernelGGL(k_gather, dim3((Nn + 3) / 4), dim3(256), 0, stream, ect, rowptr,
                     xt, bias, out, Nn, NC);
}